// Round 2
// baseline (242.455 us; speedup 1.0000x reference)
//
#include <hip/hip_runtime.h>
#include <hip/hip_bf16.h>
#include <hip/hip_cooperative_groups.h>
#include <math.h>

namespace cg = cooperative_groups;

// ---------------------------------------------------------------------------
// Metric loss (lifted structure) on MI355X — R5: fused cooperative kernel
// with runtime-sized grid + fallback.
// R4 failed with out==0 (absmax == full loss value): the cooperative launch
// was rejected (hard-coded 768 blocks vs runtime co-residency calc) and the
// error was never checked. R5:
//   * grid = min(768, occupancyMaxActiveBlocks * numCUs)  (grid-stride phases
//     make any grid size correct)
//   * launch result checked; on error -> proven R3 4-kernel path (100us)
// Phases: prep -> sync -> triangular MFMA Gram w/ row/col E-sums -> sync ->
// per-pair loss, one atomicAdd(out)/block.
// ---------------------------------------------------------------------------

typedef __bf16 bf16x8 __attribute__((ext_vector_type(8)));
typedef float floatx4 __attribute__((ext_vector_type(4)));

#define KD 256
#define NU 6144
#define NBU 48
#define TU (NBU * (NBU + 1) / 2) /* 1176 */
#define BM 128
#define BK 32
#define ECONST 2.718281828459045f
#define NBLK 768
#define LOSS_BLOCKS 1536

// logical (row r, 16B k-slot q) -> bf16 element index in swizzled LDS tile
#define LSLOT(r, q) ((((r) * 4 + ((q) ^ (((r) >> 1) & 3)))) * 8)

__device__ __forceinline__ void gload_lds16(const void* g, void* l) {
  __builtin_amdgcn_global_load_lds((const __attribute__((address_space(1))) unsigned int*)g,
                                   (__attribute__((address_space(3))) unsigned int*)l,
                                   16, 0, 0);
}

// ===========================================================================
// Fused cooperative kernel (grid-stride in every phase; any grid size works)
// ===========================================================================
__global__ __launch_bounds__(256, 3) void fused_kernel(
    const float* __restrict__ text, const float* __restrict__ shape,
    __bf16* __restrict__ Xu, float* __restrict__ sq,
    float* __restrict__ rowacc,  // [0,NU)=St, [NU,2NU)=Ss
    float* __restrict__ out, int out_n) {
  __shared__ __align__(16) __bf16 As[BM * BK];
  __shared__ __align__(16) __bf16 Bs[BM * BK];
  __shared__ float rowbuf[2][128];
  __shared__ float colbuf[2][128];
  __shared__ float part[4];

  const int tid = threadIdx.x;
  const int lane = tid & 63;
  const int w = tid >> 6;
  const int bid = blockIdx.x;
  const int nblk = gridDim.x;
  const int gt = bid * 256 + tid;

  // ===== phase 1: prep (bf16 convert unique rows, row sq; zero accums) =====
  for (int i = gt; i < 2 * NU; i += nblk * 256) rowacc[i] = 0.f;
  if (gt < out_n) out[gt] = 0.f;
  for (int wave = bid * 4 + w; wave < NU; wave += nblk * 4) {
    const float* src = (wave < 4096) ? (text + (size_t)wave * KD)
                                     : (shape + (size_t)(wave - 4096) * KD);
    __bf16* dst = Xu + (size_t)wave * KD;
    float s = 0.f;
#pragma unroll
    for (int j = 0; j < 4; ++j) {
      int idx = j * 64 + lane;
      float f = src[idx];
      __bf16 h = (__bf16)f;  // RNE
      dst[idx] = h;
      float fv = (float)h;   // square the ROUNDED value (consistency with MFMA G)
      s += fv * fv;
    }
#pragma unroll
    for (int m = 1; m < 64; m <<= 1) s += __shfl_xor(s, m, 64);
    if (lane == 0) sq[wave] = s;
  }
  __threadfence();
  cg::this_grid().sync();
  __threadfence();

  // ===== phase 2: triangular Gram + E + diag-free row/col partial sums =====
  const int warpM = w >> 1, warpN = w & 1;  // 2x2 wave grid of 64x64 tiles
  const int quad = lane >> 4;
  const int l15 = lane & 15;
  // staging: chunk c (16 rows, 1KB); lane L -> row 16c+(L>>2), swizzled k-slot
  const int sRow = lane >> 2;
  const int sCol = (((lane & 3) ^ ((lane >> 3) & 3))) * 8;
  const float L2E = 1.44269504088896f;

  for (int t = bid; t < TU; t += nblk) {
    // triangular decode: by >= bx
    int by = (int)((sqrtf(8.0f * (float)t + 1.0f) - 1.0f) * 0.5f);
    while ((by + 1) * (by + 2) / 2 <= t) ++by;
    while (by * (by + 1) / 2 > t) --by;
    const int bx = t - by * (by + 1) / 2;

    const int mBase = by * BM;  // rows (mBase >= nBase)
    const int nBase = bx * BM;  // cols
    const bool diag = (by == bx);

    floatx4 acc[4][4] = {};

    for (int kt = 0; kt < KD; kt += BK) {
      __syncthreads();
#pragma unroll
      for (int h = 0; h < 2; ++h) {
        int c = h * 4 + w;
        gload_lds16(Xu + (size_t)(mBase + c * 16 + sRow) * KD + kt + sCol, &As[c * 512]);
        gload_lds16(Xu + (size_t)(nBase + c * 16 + sRow) * KD + kt + sCol, &Bs[c * 512]);
      }
      __syncthreads();

      bf16x8 af[4], bfr[4];
#pragma unroll
      for (int tm = 0; tm < 4; ++tm)
        af[tm] = *(const bf16x8*)&As[LSLOT(warpM * 64 + tm * 16 + l15, quad)];
#pragma unroll
      for (int tn = 0; tn < 4; ++tn)
        bfr[tn] = *(const bf16x8*)&Bs[LSLOT(warpN * 64 + tn * 16 + l15, quad)];
#pragma unroll
      for (int tm = 0; tm < 4; ++tm)
#pragma unroll
        for (int tn = 0; tn < 4; ++tn)
          acc[tm][tn] = __builtin_amdgcn_mfma_f32_16x16x32_bf16(af[tm], bfr[tn], acc[tm][tn], 0, 0, 0);
    }

    // ---- epilogue: E = exp(1-D), diag-free row+col sums ----
    const int rbase = mBase + warpM * 64;
    const int cbase = nBase + warpN * 64;
    float sqr[4][4], sqc[4];
#pragma unroll
    for (int tm = 0; tm < 4; ++tm)
#pragma unroll
      for (int r = 0; r < 4; ++r)
        sqr[tm][r] = sq[rbase + tm * 16 + quad * 4 + r];
#pragma unroll
    for (int tn = 0; tn < 4; ++tn)
      sqc[tn] = sq[cbase + tn * 16 + l15];

    float cs[4] = {0.f, 0.f, 0.f, 0.f};
#pragma unroll
    for (int tm = 0; tm < 4; ++tm) {
      float rs[4] = {0.f, 0.f, 0.f, 0.f};
#pragma unroll
      for (int tn = 0; tn < 4; ++tn) {
#pragma unroll
        for (int r = 0; r < 4; ++r) {
          float v = acc[tm][tn][r];
          float dsq = fmaf(-2.0f, v, sqr[tm][r] + sqc[tn]);
          float dst = sqrtf(fmaxf(dsq, 0.f));
          float ev = __builtin_amdgcn_exp2f(fmaf(-L2E, dst, L2E));
          // unique-level diagonal excluded (handled analytically downstream)
          if (diag && tm == tn && (quad * 4 + r) == l15) ev = 0.f;
          rs[r] += ev;
          cs[tn] += ev;
        }
      }
#pragma unroll
      for (int r = 0; r < 4; ++r) {
        float v = rs[r];
        v += __shfl_xor(v, 1, 64);
        v += __shfl_xor(v, 2, 64);
        v += __shfl_xor(v, 4, 64);
        v += __shfl_xor(v, 8, 64);
        if (l15 == 0) rowbuf[warpN][warpM * 64 + tm * 16 + quad * 4 + r] = v;
      }
    }
#pragma unroll
    for (int tn = 0; tn < 4; ++tn) {
      float v = cs[tn];
      v += __shfl_xor(v, 16, 64);
      v += __shfl_xor(v, 32, 64);
      if (quad == 0) colbuf[warpM][warpN * 64 + tn * 16 + l15] = v;
    }
    __syncthreads();

    // rows -> St if cols are text (bx<32) else Ss; cols -> St if rows text
    float* rdst = rowacc + (bx < 32 ? 0 : NU);
    float* cdst = rowacc + (by < 32 ? 0 : NU);
    if (tid < 128) {
      atomicAdd(&rdst[mBase + tid], rowbuf[0][tid] + rowbuf[1][tid]);
    } else if (!diag) {
      int c = tid - 128;
      atomicAdd(&cdst[nBase + c], colbuf[0][c] + colbuf[1][c]);
    }
  }
  __threadfence();
  cg::this_grid().sync();
  __threadfence();

  // ===== phase 3: per-pair fp32 distance + analytic ns + J ================
  const float* St = rowacc;
  const float* Ss = rowacc + NU;
  float jacc = 0.f;
  for (int wv = bid * 4 + w; wv < NU; wv += nblk * 4) {
    const float *a, *b;
    float base, scale;
    if (wv < 2048) {  // tt pair p
      int p = wv;
      a = text + (size_t)(2 * p) * KD;
      b = text + (size_t)(2 * p + 1) * KD;
      base = St[2 * p] + St[2 * p + 1];
      scale = 1.0f / 4096.0f;
    } else {  // st pair
      int p = wv - 2048;
      int u1, u2;
      if (p < 2048) {  // (text_2p, shape_p)
        u1 = 2 * p; u2 = 4096 + p;
        a = text + (size_t)(2 * p) * KD;
        b = shape + (size_t)p * KD;
      } else {         // (shape_s, text_{2s+1})
        int s = p - 2048;
        u1 = 4096 + s; u2 = 2 * s + 1;
        a = shape + (size_t)s * KD;
        b = text + (size_t)(2 * s + 1) * KD;
      }
      float g1 = St[u1] + 2.0f * Ss[u1];
      float g2 = St[u2] + 2.0f * Ss[u2];
      base = g1 + g2 + ECONST;
      scale = 1.0f / 8192.0f;
    }
    float s = 0.f;
#pragma unroll
    for (int j = 0; j < 4; ++j) {
      int idx = j * 64 + lane;
      float d = a[idx] - b[idx];
      s += d * d;
    }
#pragma unroll
    for (int m = 1; m < 64; m <<= 1) s += __shfl_xor(s, m, 64);
    if (lane == 0) {
      float D = s > 0.f ? sqrtf(s) : 0.f;
      float ns = base - 2.0f * expf(1.0f - D);
      float J = logf(ns) + D;
      jacc += (J > 0.f) ? J * J * scale : 0.f;
    }
  }
  if (lane == 0) part[w] = jacc;
  __syncthreads();
  if (tid == 0) atomicAdd(out, part[0] + part[1] + part[2] + part[3]);
}

// ===========================================================================
// Fallback path: verbatim R3 four-kernel pipeline (verified, ~100us)
// ===========================================================================
__global__ __launch_bounds__(256) void prep_kernel(const float* __restrict__ text,
                                                   const float* __restrict__ shape,
                                                   __bf16* __restrict__ Xu,
                                                   float* __restrict__ sq,
                                                   float* __restrict__ rowacc) {
  int gt = blockIdx.x * 256 + threadIdx.x;
  if (gt < 2 * NU) rowacc[gt] = 0.f;
  int wave = gt >> 6;
  int lane = gt & 63;
  const float* src = (wave < 4096) ? (text + (size_t)wave * KD)
                                   : (shape + (size_t)(wave - 4096) * KD);
  __bf16* dst = Xu + (size_t)wave * KD;
  float s = 0.f;
#pragma unroll
  for (int j = 0; j < 4; ++j) {
    int idx = j * 64 + lane;
    float f = src[idx];
    __bf16 h = (__bf16)f;
    dst[idx] = h;
    float fv = (float)h;
    s += fv * fv;
  }
#pragma unroll
  for (int m = 1; m < 64; m <<= 1) s += __shfl_xor(s, m, 64);
  if (lane == 0) sq[wave] = s;
}

__global__ __launch_bounds__(256, 4) void egemm_tri_kernel(
    const __bf16* __restrict__ X, const float* __restrict__ sq,
    float* __restrict__ rowacc) {
  __shared__ __align__(16) __bf16 As[BM * BK];
  __shared__ __align__(16) __bf16 Bs[BM * BK];
  __shared__ float rowbuf[2][128];
  __shared__ float colbuf[2][128];

  int t = blockIdx.x;
  int by = (int)((sqrtf(8.0f * (float)t + 1.0f) - 1.0f) * 0.5f);
  while ((by + 1) * (by + 2) / 2 <= t) ++by;
  while (by * (by + 1) / 2 > t) --by;
  const int bx = t - by * (by + 1) / 2;

  const int mBase = by * BM;
  const int nBase = bx * BM;
  const bool diag = (by == bx);

  const int tid = threadIdx.x;
  const int lane = tid & 63;
  const int w = tid >> 6;
  const int warpM = w >> 1, warpN = w & 1;
  const int quad = lane >> 4;
  const int l15 = lane & 15;

  floatx4 acc[4][4] = {};

  const int sRow = lane >> 2;
  const int sCol = (((lane & 3) ^ ((lane >> 3) & 3))) * 8;

  for (int kt = 0; kt < KD; kt += BK) {
    __syncthreads();
#pragma unroll
    for (int h = 0; h < 2; ++h) {
      int c = h * 4 + w;
      gload_lds16(X + (size_t)(mBase + c * 16 + sRow) * KD + kt + sCol, &As[c * 512]);
      gload_lds16(X + (size_t)(nBase + c * 16 + sRow) * KD + kt + sCol, &Bs[c * 512]);
    }
    __syncthreads();

    bf16x8 af[4], bfr[4];
#pragma unroll
    for (int tm = 0; tm < 4; ++tm)
      af[tm] = *(const bf16x8*)&As[LSLOT(warpM * 64 + tm * 16 + l15, quad)];
#pragma unroll
    for (int tn = 0; tn < 4; ++tn)
      bfr[tn] = *(const bf16x8*)&Bs[LSLOT(warpN * 64 + tn * 16 + l15, quad)];
#pragma unroll
    for (int tm = 0; tm < 4; ++tm)
#pragma unroll
      for (int tn = 0; tn < 4; ++tn)
        acc[tm][tn] = __builtin_amdgcn_mfma_f32_16x16x32_bf16(af[tm], bfr[tn], acc[tm][tn], 0, 0, 0);
  }

  const int rbase = mBase + warpM * 64;
  const int cbase = nBase + warpN * 64;
  float sqr[4][4], sqc[4];
#pragma unroll
  for (int tm = 0; tm < 4; ++tm)
#pragma unroll
    for (int r = 0; r < 4; ++r)
      sqr[tm][r] = sq[rbase + tm * 16 + quad * 4 + r];
#pragma unroll
  for (int tn = 0; tn < 4; ++tn)
    sqc[tn] = sq[cbase + tn * 16 + l15];

  const float L2E = 1.44269504088896f;
  float cs[4] = {0.f, 0.f, 0.f, 0.f};
#pragma unroll
  for (int tm = 0; tm < 4; ++tm) {
    float rs[4] = {0.f, 0.f, 0.f, 0.f};
#pragma unroll
    for (int tn = 0; tn < 4; ++tn) {
#pragma unroll
      for (int r = 0; r < 4; ++r) {
        float v = acc[tm][tn][r];
        float dsq = fmaf(-2.0f, v, sqr[tm][r] + sqc[tn]);
        float dst = sqrtf(fmaxf(dsq, 0.f));
        float ev = __builtin_amdgcn_exp2f(fmaf(-L2E, dst, L2E));
        if (diag && tm == tn && (quad * 4 + r) == l15) ev = 0.f;
        rs[r] += ev;
        cs[tn] += ev;
      }
    }
#pragma unroll
    for (int r = 0; r < 4; ++r) {
      float v = rs[r];
      v += __shfl_xor(v, 1, 64);
      v += __shfl_xor(v, 2, 64);
      v += __shfl_xor(v, 4, 64);
      v += __shfl_xor(v, 8, 64);
      if (l15 == 0) rowbuf[warpN][warpM * 64 + tm * 16 + quad * 4 + r] = v;
    }
  }
#pragma unroll
  for (int tn = 0; tn < 4; ++tn) {
    float v = cs[tn];
    v += __shfl_xor(v, 16, 64);
    v += __shfl_xor(v, 32, 64);
    if (quad == 0) colbuf[warpM][warpN * 64 + tn * 16 + l15] = v;
  }
  __syncthreads();

  float* rdst = rowacc + (bx < 32 ? 0 : NU);
  float* cdst = rowacc + (by < 32 ? 0 : NU);
  if (tid < 128) {
    atomicAdd(&rdst[mBase + tid], rowbuf[0][tid] + rowbuf[1][tid]);
  } else if (!diag) {
    int c = tid - 128;
    atomicAdd(&cdst[nBase + c], colbuf[0][c] + colbuf[1][c]);
  }
}

__global__ __launch_bounds__(256) void loss_kernel(const float* __restrict__ text,
                                                   const float* __restrict__ shape,
                                                   const float* __restrict__ rowacc,
                                                   float* __restrict__ partials) {
  __shared__ float part[4];
  const float* St = rowacc;
  const float* Ss = rowacc + NU;
  int wv = blockIdx.x * 4 + (threadIdx.x >> 6);
  int lane = threadIdx.x & 63;
  const float *a, *b;
  float base, scale;
  if (wv < 2048) {
    int p = wv;
    a = text + (size_t)(2 * p) * KD;
    b = text + (size_t)(2 * p + 1) * KD;
    base = St[2 * p] + St[2 * p + 1];
    scale = 1.0f / 4096.0f;
  } else {
    int p = wv - 2048;
    int u1, u2;
    if (p < 2048) {
      u1 = 2 * p; u2 = 4096 + p;
      a = text + (size_t)(2 * p) * KD;
      b = shape + (size_t)p * KD;
    } else {
      int s = p - 2048;
      u1 = 4096 + s; u2 = 2 * s + 1;
      a = shape + (size_t)s * KD;
      b = text + (size_t)(2 * s + 1) * KD;
    }
    float g1 = St[u1] + 2.0f * Ss[u1];
    float g2 = St[u2] + 2.0f * Ss[u2];
    base = g1 + g2 + ECONST;
    scale = 1.0f / 8192.0f;
  }
  float s = 0.f;
#pragma unroll
  for (int j = 0; j < 4; ++j) {
    int idx = j * 64 + lane;
    float d = a[idx] - b[idx];
    s += d * d;
  }
#pragma unroll
  for (int m = 1; m < 64; m <<= 1) s += __shfl_xor(s, m, 64);
  if (lane == 0) {
    float D = s > 0.f ? sqrtf(s) : 0.f;
    float ns = base - 2.0f * expf(1.0f - D);
    float J = logf(ns) + D;
    part[threadIdx.x >> 6] = (J > 0.f) ? J * J * scale : 0.f;
  }
  __syncthreads();
  if (threadIdx.x == 0)
    partials[blockIdx.x] = part[0] + part[1] + part[2] + part[3];
}

__global__ __launch_bounds__(256) void reduce_kernel(const float* __restrict__ partials,
                                                     float* __restrict__ out, int out_n) {
  __shared__ float part[4];
  float s = 0.f;
  for (int i = threadIdx.x; i < LOSS_BLOCKS; i += 256) s += partials[i];
#pragma unroll
  for (int m = 1; m < 64; m <<= 1) s += __shfl_xor(s, m, 64);
  if ((threadIdx.x & 63) == 0) part[threadIdx.x >> 6] = s;
  __syncthreads();
  if (threadIdx.x == 0) out[0] = part[0] + part[1] + part[2] + part[3];
  else if (threadIdx.x < out_n) out[threadIdx.x] = 0.f;
}

// ===========================================================================
extern "C" void kernel_launch(void* const* d_in, const int* in_sizes, int n_in,
                              void* d_out, int out_size, void* d_ws, size_t ws_size,
                              hipStream_t stream) {
  const float* text = (const float*)d_in[0];
  const float* shape = (const float*)d_in[1];
  float* out = (float*)d_out;

  char* ws = (char*)d_ws;
  __bf16* Xu = (__bf16*)ws;                                // 3 MB
  float* sq = (float*)(ws + (size_t)NU * KD * 2);          // 24 KB
  float* rowacc = sq + NU;                                 // 48 KB (St ++ Ss)
  float* partials = rowacc + 2 * NU;                       // 6 KB

  // One-time: ask the RUNTIME how many blocks are co-resident (R4 hard-coded
  // 768 and the cooperative launch was rejected -> kernel never ran).
  static int coop_grid = -2;  // -2 uninit, -1 disabled
  if (coop_grid == -2) {
    hipDeviceProp_t prop;
    int maxB = 0;
    if (hipGetDeviceProperties(&prop, 0) == hipSuccess &&
        prop.cooperativeLaunch &&
        hipOccupancyMaxActiveBlocksPerMultiprocessor(
            &maxB, (const void*)fused_kernel, 256, 0) == hipSuccess &&
        maxB > 0) {
      long g = (long)maxB * prop.multiProcessorCount;
      coop_grid = (int)(g > NBLK ? NBLK : g);
    } else {
      coop_grid = -1;
    }
  }

  bool done = false;
  if (coop_grid > 0) {
    int out_n = out_size;
    void* kargs[] = {(void*)&text, (void*)&shape, (void*)&Xu, (void*)&sq,
                     (void*)&rowacc, (void*)&out, (void*)&out_n};
    hipError_t e = hipLaunchCooperativeKernel((const void*)fused_kernel,
                                              dim3(coop_grid), dim3(256), kargs,
                                              0, stream);
    if (e == hipSuccess) {
      done = true;
    } else {
      (void)hipGetLastError();  // clear sticky error, fall back
      coop_grid = -1;
    }
  }

  if (!done) {
    prep_kernel<<<NU / 4, 256, 0, stream>>>(text, shape, Xu, sq, rowacc);
    egemm_tri_kernel<<<TU, 256, 0, stream>>>(Xu, sq, rowacc);
    loss_kernel<<<LOSS_BLOCKS, 256, 0, stream>>>(text, shape, rowacc, partials);
    reduce_kernel<<<1, 256, 0, stream>>>(partials, out, out_size);
  }
}

// Round 3
// 99.588 us; speedup vs baseline: 2.4346x; 2.4346x over previous
//
#include <hip/hip_runtime.h>
#include <hip/hip_bf16.h>
#include <math.h>

// ---------------------------------------------------------------------------
// Metric loss (lifted structure) on MI355X — R6: tightened 3-kernel pipeline.
// R5 post-mortem: fused cooperative kernel = 355us with ALL pipes idle
// (MfmaUtil 1.1%, VALU 4.7%) -> grid.sync + per-thread __threadfence on
// non-coherent-L2 gfx950 costs ~300us (per-wave buffer_wbl2/inv storms).
// Grid-wide sync is abandoned; kernel boundaries provide the coherence.
// Changes vs the verified 100us R3 pipeline:
//   * egemm __launch_bounds__(256,3): R5 proved the body needs ~144 regs
//     (80 arch + 64 acc); R3's (256,4)=128-cap forced K-loop spills.
//   * loss kernel atomicAdds J^2 partials directly into out[0] (zeroed by
//     prep); reduce_kernel + partials buffer deleted (one less launch+gap).
// ---------------------------------------------------------------------------

typedef __bf16 bf16x8 __attribute__((ext_vector_type(8)));
typedef float floatx4 __attribute__((ext_vector_type(4)));

#define KD 256
#define NU 6144
#define NBU 48
#define TU (NBU * (NBU + 1) / 2) /* 1176 */
#define BM 128
#define BK 32
#define ECONST 2.718281828459045f

// logical (row r, 16B k-slot q) -> bf16 element index in swizzled LDS tile
#define LSLOT(r, q) ((((r) * 4 + ((q) ^ (((r) >> 1) & 3)))) * 8)

__device__ __forceinline__ void gload_lds16(const void* g, void* l) {
  __builtin_amdgcn_global_load_lds((const __attribute__((address_space(1))) unsigned int*)g,
                                   (__attribute__((address_space(3))) unsigned int*)l,
                                   16, 0, 0);
}

// ---- prep: bf16 convert unique rows, row sq from bf16; zero accums + out ---
__global__ __launch_bounds__(256) void prep_kernel(const float* __restrict__ text,
                                                   const float* __restrict__ shape,
                                                   __bf16* __restrict__ Xu,
                                                   float* __restrict__ sq,
                                                   float* __restrict__ rowacc,
                                                   float* __restrict__ out, int out_n) {
  int gt = blockIdx.x * 256 + threadIdx.x;
  if (gt < 2 * NU) rowacc[gt] = 0.f;  // St ++ Ss contiguous
  if (gt < out_n) out[gt] = 0.f;      // loss kernel atomicAdds into out[0]
  int wave = gt >> 6;                 // one wave per unique row, 0..6143
  int lane = gt & 63;
  const float* src = (wave < 4096) ? (text + (size_t)wave * KD)
                                   : (shape + (size_t)(wave - 4096) * KD);
  __bf16* dst = Xu + (size_t)wave * KD;
  float s = 0.f;
#pragma unroll
  for (int j = 0; j < 4; ++j) {
    int idx = j * 64 + lane;
    float f = src[idx];
    __bf16 h = (__bf16)f;  // RNE
    dst[idx] = h;
    float fv = (float)h;   // square the ROUNDED value (consistency with MFMA G)
    s += fv * fv;
  }
#pragma unroll
  for (int m = 1; m < 64; m <<= 1) s += __shfl_xor(s, m, 64);
  if (lane == 0) sq[wave] = s;
}

// ---- triangular Gram + E + diag-free row/col partial sums ------------------
// (256,3): 170-VGPR cap fits the ~144-reg body (80 arch + 64 acc, measured in
// R5's profile) with zero spill; 3 blocks/CU co-resident (LDS 17.4KB x3).
__global__ __launch_bounds__(256, 3) void egemm_tri_kernel(
    const __bf16* __restrict__ X, const float* __restrict__ sq,
    float* __restrict__ rowacc) {  // [0,NU)=St, [NU,2NU)=Ss
  __shared__ __align__(16) __bf16 As[BM * BK];
  __shared__ __align__(16) __bf16 Bs[BM * BK];
  __shared__ float rowbuf[2][128];
  __shared__ float colbuf[2][128];

  // triangular decode: by >= bx
  int t = blockIdx.x;
  int by = (int)((sqrtf(8.0f * (float)t + 1.0f) - 1.0f) * 0.5f);
  while ((by + 1) * (by + 2) / 2 <= t) ++by;
  while (by * (by + 1) / 2 > t) --by;
  const int bx = t - by * (by + 1) / 2;

  const int mBase = by * BM;  // rows (mBase >= nBase)
  const int nBase = bx * BM;  // cols
  const bool diag = (by == bx);

  const int tid = threadIdx.x;
  const int lane = tid & 63;
  const int w = tid >> 6;  // 2x2 wave grid of 64x64 tiles
  const int warpM = w >> 1, warpN = w & 1;
  const int quad = lane >> 4;
  const int l15 = lane & 15;

  floatx4 acc[4][4] = {};

  // staging: chunk c (16 rows, 1KB); lane L -> row 16c+(L>>2), swizzled k-slot
  const int sRow = lane >> 2;
  const int sCol = (((lane & 3) ^ ((lane >> 3) & 3))) * 8;

  for (int kt = 0; kt < KD; kt += BK) {
    __syncthreads();
#pragma unroll
    for (int h = 0; h < 2; ++h) {
      int c = h * 4 + w;
      gload_lds16(X + (size_t)(mBase + c * 16 + sRow) * KD + kt + sCol, &As[c * 512]);
      gload_lds16(X + (size_t)(nBase + c * 16 + sRow) * KD + kt + sCol, &Bs[c * 512]);
    }
    __syncthreads();

    bf16x8 af[4], bfr[4];
#pragma unroll
    for (int tm = 0; tm < 4; ++tm)
      af[tm] = *(const bf16x8*)&As[LSLOT(warpM * 64 + tm * 16 + l15, quad)];
#pragma unroll
    for (int tn = 0; tn < 4; ++tn)
      bfr[tn] = *(const bf16x8*)&Bs[LSLOT(warpN * 64 + tn * 16 + l15, quad)];
#pragma unroll
    for (int tm = 0; tm < 4; ++tm)
#pragma unroll
      for (int tn = 0; tn < 4; ++tn)
        acc[tm][tn] = __builtin_amdgcn_mfma_f32_16x16x32_bf16(af[tm], bfr[tn], acc[tm][tn], 0, 0, 0);
  }

  // ---- epilogue: E = exp(1-D), diag-free row+col sums ----
  const int rbase = mBase + warpM * 64;
  const int cbase = nBase + warpN * 64;
  float sqr[4][4], sqc[4];
#pragma unroll
  for (int tm = 0; tm < 4; ++tm)
#pragma unroll
    for (int r = 0; r < 4; ++r)
      sqr[tm][r] = sq[rbase + tm * 16 + quad * 4 + r];
#pragma unroll
  for (int tn = 0; tn < 4; ++tn)
    sqc[tn] = sq[cbase + tn * 16 + l15];

  const float L2E = 1.44269504088896f;
  float cs[4] = {0.f, 0.f, 0.f, 0.f};
#pragma unroll
  for (int tm = 0; tm < 4; ++tm) {
    float rs[4] = {0.f, 0.f, 0.f, 0.f};
#pragma unroll
    for (int tn = 0; tn < 4; ++tn) {
#pragma unroll
      for (int r = 0; r < 4; ++r) {
        float v = acc[tm][tn][r];
        float dsq = fmaf(-2.0f, v, sqr[tm][r] + sqc[tn]);
        float dst = sqrtf(fmaxf(dsq, 0.f));
        float ev = __builtin_amdgcn_exp2f(fmaf(-L2E, dst, L2E));
        // unique-level diagonal excluded (handled analytically downstream)
        if (diag && tm == tn && (quad * 4 + r) == l15) ev = 0.f;
        rs[r] += ev;
        cs[tn] += ev;
      }
    }
#pragma unroll
    for (int r = 0; r < 4; ++r) {
      float v = rs[r];
      v += __shfl_xor(v, 1, 64);
      v += __shfl_xor(v, 2, 64);
      v += __shfl_xor(v, 4, 64);
      v += __shfl_xor(v, 8, 64);
      if (l15 == 0) rowbuf[warpN][warpM * 64 + tm * 16 + quad * 4 + r] = v;
    }
  }
#pragma unroll
  for (int tn = 0; tn < 4; ++tn) {
    float v = cs[tn];
    v += __shfl_xor(v, 16, 64);
    v += __shfl_xor(v, 32, 64);
    if (quad == 0) colbuf[warpM][warpN * 64 + tn * 16 + l15] = v;
  }
  __syncthreads();

  // rows -> St if cols are text (bx<32) else Ss; cols -> St if rows text
  float* rdst = rowacc + (bx < 32 ? 0 : NU);
  float* cdst = rowacc + (by < 32 ? 0 : NU);
  if (tid < 128) {
    atomicAdd(&rdst[mBase + tid], rowbuf[0][tid] + rowbuf[1][tid]);
  } else if (!diag) {
    int c = tid - 128;
    atomicAdd(&cdst[nBase + c], colbuf[0][c] + colbuf[1][c]);
  }
}

// ---- per-pair fp32 distance + analytic ns + J; atomicAdd into out[0] -------
// 768 blocks x 4 waves, 2 pairs per wave (6144 pairs total).
__global__ __launch_bounds__(256) void loss_kernel(const float* __restrict__ text,
                                                   const float* __restrict__ shape,
                                                   const float* __restrict__ rowacc,
                                                   float* __restrict__ out) {
  __shared__ float part[4];
  const float* St = rowacc;
  const float* Ss = rowacc + NU;
  const int w = threadIdx.x >> 6;
  const int lane = threadIdx.x & 63;
  float jacc = 0.f;
#pragma unroll
  for (int it = 0; it < 2; ++it) {
    int wv = it * 3072 + blockIdx.x * 4 + w;  // 0..6143, exact cover
    const float *a, *b;
    float base, scale;
    if (wv < 2048) {  // tt pair p
      int p = wv;
      a = text + (size_t)(2 * p) * KD;
      b = text + (size_t)(2 * p + 1) * KD;
      base = St[2 * p] + St[2 * p + 1];
      scale = 1.0f / 4096.0f;
    } else {  // st pair
      int p = wv - 2048;
      int u1, u2;
      if (p < 2048) {  // (text_2p, shape_p)
        u1 = 2 * p; u2 = 4096 + p;
        a = text + (size_t)(2 * p) * KD;
        b = shape + (size_t)p * KD;
      } else {         // (shape_s, text_{2s+1})
        int s = p - 2048;
        u1 = 4096 + s; u2 = 2 * s + 1;
        a = shape + (size_t)s * KD;
        b = text + (size_t)(2 * s + 1) * KD;
      }
      float g1 = St[u1] + 2.0f * Ss[u1];
      float g2 = St[u2] + 2.0f * Ss[u2];
      base = g1 + g2 + ECONST;
      scale = 1.0f / 8192.0f;
    }
    float s = 0.f;
#pragma unroll
    for (int j = 0; j < 4; ++j) {
      int idx = j * 64 + lane;
      float d = a[idx] - b[idx];
      s += d * d;
    }
#pragma unroll
    for (int m = 1; m < 64; m <<= 1) s += __shfl_xor(s, m, 64);
    if (lane == 0) {
      float D = s > 0.f ? sqrtf(s) : 0.f;
      float ns = base - 2.0f * expf(1.0f - D);
      float J = logf(ns) + D;
      jacc += (J > 0.f) ? J * J * scale : 0.f;
    }
  }
  if (lane == 0) part[w] = jacc;
  __syncthreads();
  if (threadIdx.x == 0) atomicAdd(out, part[0] + part[1] + part[2] + part[3]);
}

extern "C" void kernel_launch(void* const* d_in, const int* in_sizes, int n_in,
                              void* d_out, int out_size, void* d_ws, size_t ws_size,
                              hipStream_t stream) {
  const float* text = (const float*)d_in[0];
  const float* shape = (const float*)d_in[1];
  float* out = (float*)d_out;

  char* ws = (char*)d_ws;
  __bf16* Xu = (__bf16*)ws;                                // 3 MB
  float* sq = (float*)(ws + (size_t)NU * KD * 2);          // 24 KB
  float* rowacc = sq + NU;                                 // 48 KB (St ++ Ss)

  prep_kernel<<<NU / 4, 256, 0, stream>>>(text, shape, Xu, sq, rowacc, out, out_size);
  egemm_tri_kernel<<<TU, 256, 0, stream>>>(Xu, sq, rowacc);
  loss_kernel<<<768, 256, 0, stream>>>(text, shape, rowacc, out);
}